// Round 4
// baseline (1071.165 us; speedup 1.0000x reference)
//
#include <hip/hip_runtime.h>
#include <math.h>

// Problem constants (B, L, H, DH, DV) = (4, 4096, 16, 128, 128), CHUNK=1024
#define Bb   4
#define Ll   4096
#define Hh   16
#define DHd  128
#define DVd  128
#define CHk  1024
#define NCc  4

typedef __bf16 bf16x8 __attribute__((ext_vector_type(8)));
typedef float  f32x4  __attribute__((ext_vector_type(4)));

static __device__ __forceinline__ unsigned short f32_to_bf16(float f) {
  unsigned int u = __float_as_uint(f);
  u += 0x7FFFu + ((u >> 16) & 1u);   // round-to-nearest-even
  return (unsigned short)(u >> 16);
}

// ---------------- kernel 1: RoPE cos/sin table [L][64] ----------------
__global__ void rope_table_k(float2* __restrict__ table) {
  int idx = blockIdx.x * 256 + threadIdx.x;
  if (idx >= Ll * 64) return;
  int l = idx >> 6, j = idx & 63;
  float inv_freq = expf((float)j * (-logf(10000.0f) / 64.0f));
  float ang = (float)l * inv_freq;
  float s, c;
  sincosf(ang, &s, &c);
  table[idx] = make_float2(c, s);
}

// ---- kernel 2: fused preprocess per (b,n,h,64-row slab):
//      RoPE+scale+bf16 for q,k  +  V transpose to vt[dv][kv] ----
__global__ void pre_k(const float4* __restrict__ q4, const float4* __restrict__ k4,
                      const float4* __restrict__ v4, const float4* __restrict__ tb4,
                      ushort4* __restrict__ qr4, ushort4* __restrict__ kr4,
                      unsigned short* __restrict__ vt) {
  int bid = blockIdx.x;            // (b,n,h,kb): 4*4*16*16 = 4096 blocks
  int kb = bid & 15;               // 64-row slab
  int h  = (bid >> 4) & 15;
  int n  = (bid >> 8) & 3;
  int b  = bid >> 10;
  int tid = threadIdx.x;
  int l0 = n * CHk + kb * 64;

  // ---- RoPE for q,k: 64 rows x 16 j4-quads ----
#pragma unroll
  for (int it = 0; it < 4; ++it) {
    int w  = it * 256 + tid;
    int j4 = w & 15;
    int r  = w >> 4;
    int l  = l0 + r;
    long base4 = ((long)((b * Ll + l) * Hh + h)) * 32;
    float4 cs0 = tb4[(long)l * 32 + j4 * 2];      // c0 s0 c1 s1
    float4 cs1 = tb4[(long)l * 32 + j4 * 2 + 1];  // c2 s2 c3 s3
    float4 a1 = q4[base4 + j4];
    float4 a2 = q4[base4 + 16 + j4];
    float4 b1 = k4[base4 + j4];
    float4 b2 = k4[base4 + 16 + j4];
    const float sc = 0.08838834764831845f;  // 1/sqrt(128), folded into q
    ushort4 o;
    o.x = f32_to_bf16((a1.x * cs0.x - a2.x * cs0.y) * sc);
    o.y = f32_to_bf16((a1.y * cs0.z - a2.y * cs0.w) * sc);
    o.z = f32_to_bf16((a1.z * cs1.x - a2.z * cs1.y) * sc);
    o.w = f32_to_bf16((a1.w * cs1.z - a2.w * cs1.w) * sc);
    qr4[base4 + j4] = o;
    o.x = f32_to_bf16((a1.x * cs0.y + a2.x * cs0.x) * sc);
    o.y = f32_to_bf16((a1.y * cs0.w + a2.y * cs0.z) * sc);
    o.z = f32_to_bf16((a1.z * cs1.y + a2.z * cs1.x) * sc);
    o.w = f32_to_bf16((a1.w * cs1.w + a2.w * cs1.z) * sc);
    qr4[base4 + 16 + j4] = o;
    o.x = f32_to_bf16(b1.x * cs0.x - b2.x * cs0.y);
    o.y = f32_to_bf16(b1.y * cs0.z - b2.y * cs0.w);
    o.z = f32_to_bf16(b1.z * cs1.x - b2.z * cs1.y);
    o.w = f32_to_bf16(b1.w * cs1.z - b2.w * cs1.w);
    kr4[base4 + j4] = o;
    o.x = f32_to_bf16(b1.x * cs0.y + b2.x * cs0.x);
    o.y = f32_to_bf16(b1.y * cs0.w + b2.y * cs0.z);
    o.z = f32_to_bf16(b1.z * cs1.y + b2.z * cs1.x);
    o.w = f32_to_bf16(b1.w * cs1.w + b2.w * cs1.z);
    kr4[base4 + 16 + j4] = o;
  }

  // ---- V transpose via LDS ----
  __shared__ __align__(16) unsigned short tile[DVd][68];
#pragma unroll
  for (int it = 0; it < 8; ++it) {
    int i4 = it * 256 + tid;       // 2048 float4 = 64 rows x 32 quads
    int r  = i4 >> 5;
    int c4 = i4 & 31;
    float4 val = v4[((long)((b * Ll + l0 + r) * Hh + h)) * 32 + c4];
    tile[c4 * 4 + 0][r] = f32_to_bf16(val.x);
    tile[c4 * 4 + 1][r] = f32_to_bf16(val.y);
    tile[c4 * 4 + 2][r] = f32_to_bf16(val.z);
    tile[c4 * 4 + 3][r] = f32_to_bf16(val.w);
  }
  __syncthreads();
  long ob = ((long)((b * NCc + n) * Hh + h)) * (DVd * CHk) + kb * 64;
#pragma unroll
  for (int it = 0; it < 8; ++it) {
    int i4 = it * 256 + tid;       // 2048 ushort4 = 128 dv x 16
    int dv  = i4 >> 4;
    int k4i = i4 & 15;
    ushort4 o = *(const ushort4*)&tile[dv][k4i * 4];
    *(ushort4*)&vt[ob + (long)dv * CHk + k4i * 4] = o;
  }
}

// ---- reg-staging: K tile [64][128] + Vt tile [128][64], 8 float4/thread ----
__device__ __forceinline__ void stage_load(const unsigned short* krb,
                                           const unsigned short* vtb,
                                           int kvb, int tid,
                                           float4* kreg, float4* vreg) {
#pragma unroll
  for (int i = 0; i < 4; ++i) {
    int t = i * 256 + tid;
    kreg[i] = *(const float4*)((const char*)(krb + (long)(kvb + (t >> 4)) * (Hh * DHd)) +
                               (t & 15) * 16);
  }
#pragma unroll
  for (int i = 0; i < 4; ++i) {
    int t = i * 256 + tid;
    vreg[i] = *(const float4*)((const char*)(vtb + (long)(t >> 3) * CHk + kvb) +
                               (t & 7) * 16);
  }
}

// write with XOR swizzle: LDS[row][c ^ (row&7)] (16B granules)
__device__ __forceinline__ void stage_write(unsigned short* Kb, unsigned short* Vb,
                                            int tid, const float4* kreg, const float4* vreg) {
#pragma unroll
  for (int i = 0; i < 4; ++i) {
    int t = i * 256 + tid;
    int row = t >> 4, c = (t & 15) ^ (row & 7);
    *(float4*)((char*)Kb + row * 256 + c * 16) = kreg[i];
  }
#pragma unroll
  for (int i = 0; i < 4; ++i) {
    int t = i * 256 + tid;
    int row = t >> 3, c = (t & 7) ^ (row & 7);
    *(float4*)((char*)Vb + row * 128 + c * 16) = vreg[i];
  }
}

// ---------------- kernel 3: chunk-causal flash attention ----------------
// 4 waves, 64 q-rows/block (16/wave), KV tiles of 64.
// Single-buffered LDS (42 KB -> 3 blocks/CU) + async reg-stage split (T14).
__global__ __launch_bounds__(256, 3)
void attn_k(const unsigned short* __restrict__ qr,
            const unsigned short* __restrict__ kr,
            const unsigned short* __restrict__ vt,
            float* __restrict__ out) {
  __shared__ __align__(16) unsigned short Klds[64 * 128];   // swizzled
  __shared__ __align__(16) unsigned short Vlds[128 * 64];   // swizzled
  __shared__ __align__(16) unsigned short plds[4][16][72];  // per-wave P, padded

  int bid = blockIdx.x;
  int qt = 15 - (bid & 15);        // reversed: heavy blocks first
  int h  = (bid >> 4) & 15;
  int n  = (bid >> 8) & 3;
  int b  = bid >> 10;
  int tid  = threadIdx.x;
  int wid  = tid >> 6;
  int lane = tid & 63;
  int lg = lane >> 4;
  int lc = lane & 15;

  const unsigned short* krb = kr + ((long)((b * Ll + n * CHk) * Hh + h)) * DHd;
  const unsigned short* vtb = vt + ((long)((b * NCc + n) * Hh + h)) * (DVd * CHk);

  int qrow0 = qt * 64 + wid * 16;
  const unsigned short* qrow =
      qr + ((long)((b * Ll + n * CHk + qrow0 + lc) * Hh + h)) * DHd;
  bf16x8 qf[4];
#pragma unroll
  for (int ks = 0; ks < 4; ++ks)
    qf[ks] = *reinterpret_cast<const bf16x8*>(qrow + ks * 32 + lg * 8);

  f32x4 oacc[8];
#pragma unroll
  for (int i = 0; i < 8; ++i) oacc[i] = (f32x4){0.f, 0.f, 0.f, 0.f};
  float mrow[4], lrow[4];
#pragma unroll
  for (int r = 0; r < 4; ++r) { mrow[r] = -3.0e38f; lrow[r] = 0.f; }

  // prologue: tile0 -> LDS; tile1 loads in flight
  float4 kreg[4], vreg[4];
  stage_load(krb, vtb, 0, tid, kreg, vreg);
  stage_write(Klds, Vlds, tid, kreg, vreg);
  if (qt > 0) stage_load(krb, vtb, 64, tid, kreg, vreg);
  __syncthreads();

  int swz = (lc & 7) << 4;         // read-side XOR swizzle
  for (int kvt = 0; kvt <= qt; ++kvt) {
    int kvb = kvt * 64;

    // ---- S = Q K^T over 64 kv cols (4 D-tiles of 16) ----
    const char* Kb = (const char*)&Klds[0];
    f32x4 sacc[4];
#pragma unroll
    for (int ct = 0; ct < 4; ++ct) sacc[ct] = (f32x4){0.f, 0.f, 0.f, 0.f};
#pragma unroll
    for (int ct = 0; ct < 4; ++ct) {
      int rowb = (ct * 16 + lc) * 256;
#pragma unroll
      for (int ks = 0; ks < 4; ++ks) {
        bf16x8 kf = *(const bf16x8*)(Kb + rowb + ((ks * 64 + lg * 16) ^ swz));
        sacc[ct] = __builtin_amdgcn_mfma_f32_16x16x32_bf16(qf[ks], kf, sacc[ct], 0, 0, 0);
      }
    }

    // ---- causal mask (diagonal tile only) + online softmax ----
    float p[4][4];
#pragma unroll
    for (int ct = 0; ct < 4; ++ct)
#pragma unroll
      for (int r = 0; r < 4; ++r) p[ct][r] = sacc[ct][r];
    if (kvt == qt) {
#pragma unroll
      for (int ct = 0; ct < 4; ++ct) {
        int col = kvb + ct * 16 + lc;
#pragma unroll
        for (int r = 0; r < 4; ++r)
          if (col > qrow0 + lg * 4 + r) p[ct][r] = -3.0e38f;
      }
    }
#pragma unroll
    for (int r = 0; r < 4; ++r) {
      float tmax = fmaxf(fmaxf(p[0][r], p[1][r]), fmaxf(p[2][r], p[3][r]));
      tmax = fmaxf(tmax, __shfl_xor(tmax, 1));
      tmax = fmaxf(tmax, __shfl_xor(tmax, 2));
      tmax = fmaxf(tmax, __shfl_xor(tmax, 4));
      tmax = fmaxf(tmax, __shfl_xor(tmax, 8));
      float mnew = fmaxf(mrow[r], tmax);
      float corr = __expf(mrow[r] - mnew);
      mrow[r] = mnew;
      float ps = 0.f;
#pragma unroll
      for (int ct = 0; ct < 4; ++ct) {
        p[ct][r] = __expf(p[ct][r] - mnew);
        ps += p[ct][r];
      }
      ps += __shfl_xor(ps, 1);
      ps += __shfl_xor(ps, 2);
      ps += __shfl_xor(ps, 4);
      ps += __shfl_xor(ps, 8);
      lrow[r] = lrow[r] * corr + ps;
#pragma unroll
      for (int dt = 0; dt < 8; ++dt) oacc[dt][r] *= corr;
    }

    // ---- P (D-layout) -> per-wave LDS -> A-fragment layout ----
#pragma unroll
    for (int ct = 0; ct < 4; ++ct)
#pragma unroll
      for (int r = 0; r < 4; ++r)
        plds[wid][lg * 4 + r][ct * 16 + lc] = f32_to_bf16(p[ct][r]);
    // same-wave DS ops are in-order; aliasing orders write->read
    const char* Pb = (const char*)&plds[wid][0][0];
    bf16x8 pf0 = *(const bf16x8*)(Pb + lc * 144 + lg * 16);
    bf16x8 pf1 = *(const bf16x8*)(Pb + lc * 144 + 64 + lg * 16);

    // ---- O += P V (8 dv-tiles of 16, two k-halves) ----
    const char* Vb = (const char*)&Vlds[0];
#pragma unroll
    for (int dt = 0; dt < 8; ++dt) {
      int rowb = (dt * 16 + lc) * 128;
      bf16x8 vf0 = *(const bf16x8*)(Vb + rowb + ((lg * 16) ^ swz));
      bf16x8 vf1 = *(const bf16x8*)(Vb + rowb + ((64 + lg * 16) ^ swz));
      oacc[dt] = __builtin_amdgcn_mfma_f32_16x16x32_bf16(pf0, vf0, oacc[dt], 0, 0, 0);
      oacc[dt] = __builtin_amdgcn_mfma_f32_16x16x32_bf16(pf1, vf1, oacc[dt], 0, 0, 0);
    }

    // ---- async-stage split: publish tile kvt+1, issue loads for kvt+2 ----
    if (kvt < qt) {
      __syncthreads();             // all waves done reading tile kvt
      stage_write(Klds, Vlds, tid, kreg, vreg);   // waits vmcnt as needed
      if (kvt + 1 < qt) stage_load(krb, vtb, kvb + 128, tid, kreg, vreg);
      __syncthreads();             // tile kvt+1 visible
    }
  }

  // ---- epilogue: normalize and store f32 ----
  long ob = (long)(b * Ll + n * CHk + qrow0 + lg * 4) * (Hh * DVd) + h * DVd + lc;
#pragma unroll
  for (int r = 0; r < 4; ++r) {
    float invl = 1.0f / lrow[r];
#pragma unroll
    for (int dt = 0; dt < 8; ++dt)
      out[ob + (long)r * (Hh * DVd) + dt * 16] = oacc[dt][r] * invl;
  }
}

extern "C" void kernel_launch(void* const* d_in, const int* in_sizes, int n_in,
                              void* d_out, int out_size, void* d_ws, size_t ws_size,
                              hipStream_t stream) {
  const float* q = (const float*)d_in[0];
  const float* k = (const float*)d_in[1];
  const float* v = (const float*)d_in[2];
  float* out = (float*)d_out;

  // workspace layout: table(2MB) | qr(67MB) | kr(67MB) | vt(67MB)
  char* ws = (char*)d_ws;
  float2* table = (float2*)ws;
  unsigned short* qrw = (unsigned short*)(ws + (2l << 20));
  unsigned short* krw = qrw + (long)Bb * Ll * Hh * DHd;
  unsigned short* vtw = krw + (long)Bb * Ll * Hh * DHd;

  hipLaunchKernelGGL(rope_table_k, dim3((Ll * 64) / 256), dim3(256), 0, stream, table);
  hipLaunchKernelGGL(pre_k, dim3(Bb * NCc * Hh * 16), dim3(256), 0, stream,
                     (const float4*)q, (const float4*)k, (const float4*)v,
                     (const float4*)table, (ushort4*)qrw, (ushort4*)krw, vtw);
  hipLaunchKernelGGL(attn_k, dim3(Bb * NCc * Hh * 16), dim3(256), 0, stream,
                     qrw, krw, vtw, out);
}

// Round 5
// 685.655 us; speedup vs baseline: 1.5623x; 1.5623x over previous
//
#include <hip/hip_runtime.h>
#include <math.h>

// Problem constants (B, L, H, DH, DV) = (4, 4096, 16, 128, 128), CHUNK=1024
#define Bb   4
#define Ll   4096
#define Hh   16
#define DHd  128
#define DVd  128
#define CHk  1024
#define NCc  4

typedef __bf16 bf16x8 __attribute__((ext_vector_type(8)));
typedef float  f32x4  __attribute__((ext_vector_type(4)));

static __device__ __forceinline__ unsigned short f32_to_bf16(float f) {
  unsigned int u = __float_as_uint(f);
  u += 0x7FFFu + ((u >> 16) & 1u);   // round-to-nearest-even
  return (unsigned short)(u >> 16);
}

// ---------------- kernel 1: RoPE cos/sin table [L][64] ----------------
__global__ void rope_table_k(float2* __restrict__ table) {
  int idx = blockIdx.x * 256 + threadIdx.x;
  if (idx >= Ll * 64) return;
  int l = idx >> 6, j = idx & 63;
  float inv_freq = expf((float)j * (-logf(10000.0f) / 64.0f));
  float ang = (float)l * inv_freq;
  float s, c;
  sincosf(ang, &s, &c);
  table[idx] = make_float2(c, s);
}

// ---- kernel 2: fused preprocess per (b,n,h,64-row slab):
//      RoPE+scale+bf16 for q,k  +  V transpose to vt[dv][kv] ----
__global__ void pre_k(const float4* __restrict__ q4, const float4* __restrict__ k4,
                      const float4* __restrict__ v4, const float4* __restrict__ tb4,
                      ushort4* __restrict__ qr4, ushort4* __restrict__ kr4,
                      unsigned short* __restrict__ vt) {
  int bid = blockIdx.x;            // (b,n,h,kb): 4*4*16*16 = 4096 blocks
  int kb = bid & 15;               // 64-row slab
  int h  = (bid >> 4) & 15;
  int n  = (bid >> 8) & 3;
  int b  = bid >> 10;
  int tid = threadIdx.x;
  int l0 = n * CHk + kb * 64;

  // ---- RoPE for q,k: 64 rows x 16 j4-quads ----
#pragma unroll
  for (int it = 0; it < 4; ++it) {
    int w  = it * 256 + tid;
    int j4 = w & 15;
    int r  = w >> 4;
    int l  = l0 + r;
    long base4 = ((long)((b * Ll + l) * Hh + h)) * 32;
    float4 cs0 = tb4[(long)l * 32 + j4 * 2];      // c0 s0 c1 s1
    float4 cs1 = tb4[(long)l * 32 + j4 * 2 + 1];  // c2 s2 c3 s3
    float4 a1 = q4[base4 + j4];
    float4 a2 = q4[base4 + 16 + j4];
    float4 b1 = k4[base4 + j4];
    float4 b2 = k4[base4 + 16 + j4];
    const float sc = 0.08838834764831845f;  // 1/sqrt(128), folded into q
    ushort4 o;
    o.x = f32_to_bf16((a1.x * cs0.x - a2.x * cs0.y) * sc);
    o.y = f32_to_bf16((a1.y * cs0.z - a2.y * cs0.w) * sc);
    o.z = f32_to_bf16((a1.z * cs1.x - a2.z * cs1.y) * sc);
    o.w = f32_to_bf16((a1.w * cs1.z - a2.w * cs1.w) * sc);
    qr4[base4 + j4] = o;
    o.x = f32_to_bf16((a1.x * cs0.y + a2.x * cs0.x) * sc);
    o.y = f32_to_bf16((a1.y * cs0.w + a2.y * cs0.z) * sc);
    o.z = f32_to_bf16((a1.z * cs1.y + a2.z * cs1.x) * sc);
    o.w = f32_to_bf16((a1.w * cs1.w + a2.w * cs1.z) * sc);
    qr4[base4 + 16 + j4] = o;
    o.x = f32_to_bf16(b1.x * cs0.x - b2.x * cs0.y);
    o.y = f32_to_bf16(b1.y * cs0.z - b2.y * cs0.w);
    o.z = f32_to_bf16(b1.z * cs1.x - b2.z * cs1.y);
    o.w = f32_to_bf16(b1.w * cs1.z - b2.w * cs1.w);
    kr4[base4 + j4] = o;
    o.x = f32_to_bf16(b1.x * cs0.y + b2.x * cs0.x);
    o.y = f32_to_bf16(b1.y * cs0.w + b2.y * cs0.z);
    o.z = f32_to_bf16(b1.z * cs1.y + b2.z * cs1.x);
    o.w = f32_to_bf16(b1.w * cs1.w + b2.w * cs1.z);
    kr4[base4 + 16 + j4] = o;
  }

  // ---- V transpose via LDS ----
  __shared__ __align__(16) unsigned short tile[DVd][68];
#pragma unroll
  for (int it = 0; it < 8; ++it) {
    int i4 = it * 256 + tid;       // 2048 float4 = 64 rows x 32 quads
    int r  = i4 >> 5;
    int c4 = i4 & 31;
    float4 val = v4[((long)((b * Ll + l0 + r) * Hh + h)) * 32 + c4];
    tile[c4 * 4 + 0][r] = f32_to_bf16(val.x);
    tile[c4 * 4 + 1][r] = f32_to_bf16(val.y);
    tile[c4 * 4 + 2][r] = f32_to_bf16(val.z);
    tile[c4 * 4 + 3][r] = f32_to_bf16(val.w);
  }
  __syncthreads();
  long ob = ((long)((b * NCc + n) * Hh + h)) * (DVd * CHk) + kb * 64;
#pragma unroll
  for (int it = 0; it < 8; ++it) {
    int i4 = it * 256 + tid;       // 2048 ushort4 = 128 dv x 16
    int dv  = i4 >> 4;
    int k4i = i4 & 15;
    ushort4 o = *(const ushort4*)&tile[dv][k4i * 4];
    *(ushort4*)&vt[ob + (long)dv * CHk + k4i * 4] = o;
  }
}

// ---------------- kernel 3: chunk-causal flash attention ----------------
// 4 waves, 64 q-rows/block (16/wave), KV tiles of 64.
// Single-buffered LDS (42 KB -> 3 blocks/CU) + async reg-stage split (T14).
// Staging values are NAMED float4 scalars (rule #20: no address-taken arrays).
__global__ __launch_bounds__(256, 3)
void attn_k(const unsigned short* __restrict__ qr,
            const unsigned short* __restrict__ kr,
            const unsigned short* __restrict__ vt,
            float* __restrict__ out) {
  __shared__ __align__(16) unsigned short Klds[64 * 128];   // swizzled
  __shared__ __align__(16) unsigned short Vlds[128 * 64];   // swizzled
  __shared__ __align__(16) unsigned short plds[4][16][72];  // per-wave P, padded

  int bid = blockIdx.x;
  int qt = 15 - (bid & 15);        // reversed: heavy blocks first
  int h  = (bid >> 4) & 15;
  int n  = (bid >> 8) & 3;
  int b  = bid >> 10;
  int tid  = threadIdx.x;
  int wid  = tid >> 6;
  int lane = tid & 63;
  int lg = lane >> 4;
  int lc = lane & 15;

  const unsigned short* krb = kr + ((long)((b * Ll + n * CHk) * Hh + h)) * DHd;
  const unsigned short* vtb = vt + ((long)((b * NCc + n) * Hh + h)) * (DVd * CHk);

  // per-thread staging geometry (loop-invariant: (i*16)&7 == 0, (i*32)&7 == 0)
  int krow = tid >> 4, kcol = tid & 15;          // K: rows krow+16i, granule kcol
  int vrow = tid >> 3, vcol = tid & 7;           // V: rows vrow+32i, granule vcol
  const char* ksrc0 = (const char*)(krb + (long)krow * (Hh * DHd)) + kcol * 16;
  const char* vsrc0 = (const char*)(vtb + (long)vrow * CHk) + vcol * 16;
  char* kdst = (char*)Klds + krow * 256 + ((kcol ^ (krow & 7)) * 16);
  char* vdst = (char*)Vlds + vrow * 128 + ((vcol ^ (vrow & 7)) * 16);

  float4 sk0, sk1, sk2, sk3, sv0, sv1, sv2, sv3;

#define STAGE_LOAD(kvb_) do {                                              \
    const char* kp_ = ksrc0 + (long)(kvb_) * (Hh * DHd * 2);               \
    const char* vp_ = vsrc0 + (kvb_) * 2;                                  \
    sk0 = *(const float4*)(kp_);                                           \
    sk1 = *(const float4*)(kp_ + 16l * (Hh * DHd * 2));                    \
    sk2 = *(const float4*)(kp_ + 32l * (Hh * DHd * 2));                    \
    sk3 = *(const float4*)(kp_ + 48l * (Hh * DHd * 2));                    \
    sv0 = *(const float4*)(vp_);                                           \
    sv1 = *(const float4*)(vp_ + 32l * (CHk * 2));                         \
    sv2 = *(const float4*)(vp_ + 64l * (CHk * 2));                         \
    sv3 = *(const float4*)(vp_ + 96l * (CHk * 2));                         \
  } while (0)

#define STAGE_WRITE() do {                                                 \
    *(float4*)(kdst + 0 * 16 * 256) = sk0;                                 \
    *(float4*)(kdst + 1 * 16 * 256) = sk1;                                 \
    *(float4*)(kdst + 2 * 16 * 256) = sk2;                                 \
    *(float4*)(kdst + 3 * 16 * 256) = sk3;                                 \
    *(float4*)(vdst + 0 * 32 * 128) = sv0;                                 \
    *(float4*)(vdst + 1 * 32 * 128) = sv1;                                 \
    *(float4*)(vdst + 2 * 32 * 128) = sv2;                                 \
    *(float4*)(vdst + 3 * 32 * 128) = sv3;                                 \
  } while (0)

  int qrow0 = qt * 64 + wid * 16;
  const unsigned short* qrow =
      qr + ((long)((b * Ll + n * CHk + qrow0 + lc) * Hh + h)) * DHd;
  bf16x8 qf[4];
#pragma unroll
  for (int ks = 0; ks < 4; ++ks)
    qf[ks] = *reinterpret_cast<const bf16x8*>(qrow + ks * 32 + lg * 8);

  f32x4 oacc[8];
#pragma unroll
  for (int i = 0; i < 8; ++i) oacc[i] = (f32x4){0.f, 0.f, 0.f, 0.f};
  float mrow[4], lrow[4];
#pragma unroll
  for (int r = 0; r < 4; ++r) { mrow[r] = -3.0e38f; lrow[r] = 0.f; }

  // prologue: tile0 -> LDS; tile1 loads in flight
  STAGE_LOAD(0);
  STAGE_WRITE();
  if (qt > 0) STAGE_LOAD(64);
  __syncthreads();

  int swz = (lc & 7) << 4;         // read-side XOR swizzle
  for (int kvt = 0; kvt <= qt; ++kvt) {
    int kvb = kvt * 64;

    // ---- S = Q K^T over 64 kv cols (4 D-tiles of 16) ----
    const char* Kb = (const char*)&Klds[0];
    f32x4 sacc[4];
#pragma unroll
    for (int ct = 0; ct < 4; ++ct) sacc[ct] = (f32x4){0.f, 0.f, 0.f, 0.f};
#pragma unroll
    for (int ct = 0; ct < 4; ++ct) {
      int rowb = (ct * 16 + lc) * 256;
#pragma unroll
      for (int ks = 0; ks < 4; ++ks) {
        bf16x8 kf = *(const bf16x8*)(Kb + rowb + ((ks * 64 + lg * 16) ^ swz));
        sacc[ct] = __builtin_amdgcn_mfma_f32_16x16x32_bf16(qf[ks], kf, sacc[ct], 0, 0, 0);
      }
    }

    // ---- causal mask (diagonal tile only) + online softmax ----
    float p[4][4];
#pragma unroll
    for (int ct = 0; ct < 4; ++ct)
#pragma unroll
      for (int r = 0; r < 4; ++r) p[ct][r] = sacc[ct][r];
    if (kvt == qt) {
#pragma unroll
      for (int ct = 0; ct < 4; ++ct) {
        int col = kvb + ct * 16 + lc;
#pragma unroll
        for (int r = 0; r < 4; ++r)
          if (col > qrow0 + lg * 4 + r) p[ct][r] = -3.0e38f;
      }
    }
#pragma unroll
    for (int r = 0; r < 4; ++r) {
      float tmax = fmaxf(fmaxf(p[0][r], p[1][r]), fmaxf(p[2][r], p[3][r]));
      tmax = fmaxf(tmax, __shfl_xor(tmax, 1));
      tmax = fmaxf(tmax, __shfl_xor(tmax, 2));
      tmax = fmaxf(tmax, __shfl_xor(tmax, 4));
      tmax = fmaxf(tmax, __shfl_xor(tmax, 8));
      float mnew = fmaxf(mrow[r], tmax);
      float corr = __expf(mrow[r] - mnew);
      mrow[r] = mnew;
      float ps = 0.f;
#pragma unroll
      for (int ct = 0; ct < 4; ++ct) {
        p[ct][r] = __expf(p[ct][r] - mnew);
        ps += p[ct][r];
      }
      ps += __shfl_xor(ps, 1);
      ps += __shfl_xor(ps, 2);
      ps += __shfl_xor(ps, 4);
      ps += __shfl_xor(ps, 8);
      lrow[r] = lrow[r] * corr + ps;
#pragma unroll
      for (int dt = 0; dt < 8; ++dt) oacc[dt][r] *= corr;
    }

    // ---- P (D-layout) -> per-wave LDS -> A-fragment layout ----
#pragma unroll
    for (int ct = 0; ct < 4; ++ct)
#pragma unroll
      for (int r = 0; r < 4; ++r)
        plds[wid][lg * 4 + r][ct * 16 + lc] = f32_to_bf16(p[ct][r]);
    // same-wave DS ops are in-order; aliasing orders write->read
    const char* Pb = (const char*)&plds[wid][0][0];
    bf16x8 pf0 = *(const bf16x8*)(Pb + lc * 144 + lg * 16);
    bf16x8 pf1 = *(const bf16x8*)(Pb + lc * 144 + 64 + lg * 16);

    // ---- O += P V (8 dv-tiles of 16, two k-halves) ----
    const char* Vb = (const char*)&Vlds[0];
#pragma unroll
    for (int dt = 0; dt < 8; ++dt) {
      int rowb = (dt * 16 + lc) * 128;
      bf16x8 vf0 = *(const bf16x8*)(Vb + rowb + ((lg * 16) ^ swz));
      bf16x8 vf1 = *(const bf16x8*)(Vb + rowb + ((64 + lg * 16) ^ swz));
      oacc[dt] = __builtin_amdgcn_mfma_f32_16x16x32_bf16(pf0, vf0, oacc[dt], 0, 0, 0);
      oacc[dt] = __builtin_amdgcn_mfma_f32_16x16x32_bf16(pf1, vf1, oacc[dt], 0, 0, 0);
    }

    // ---- async-stage split: publish tile kvt+1, issue loads for kvt+2 ----
    if (kvt < qt) {
      __syncthreads();             // all waves done reading tile kvt
      STAGE_WRITE();               // waits vmcnt as needed
      if (kvt + 1 < qt) STAGE_LOAD(kvb + 128);
      __syncthreads();             // tile kvt+1 visible
    }
  }

  // ---- epilogue: normalize and store f32 ----
  long ob = (long)(b * Ll + n * CHk + qrow0 + lg * 4) * (Hh * DVd) + h * DVd + lc;
#pragma unroll
  for (int r = 0; r < 4; ++r) {
    float invl = 1.0f / lrow[r];
#pragma unroll
    for (int dt = 0; dt < 8; ++dt)
      out[ob + (long)r * (Hh * DVd) + dt * 16] = oacc[dt][r] * invl;
  }
}

extern "C" void kernel_launch(void* const* d_in, const int* in_sizes, int n_in,
                              void* d_out, int out_size, void* d_ws, size_t ws_size,
                              hipStream_t stream) {
  const float* q = (const float*)d_in[0];
  const float* k = (const float*)d_in[1];
  const float* v = (const float*)d_in[2];
  float* out = (float*)d_out;

  // workspace layout: table(2MB) | qr(67MB) | kr(67MB) | vt(67MB)
  char* ws = (char*)d_ws;
  float2* table = (float2*)ws;
  unsigned short* qrw = (unsigned short*)(ws + (2l << 20));
  unsigned short* krw = qrw + (long)Bb * Ll * Hh * DHd;
  unsigned short* vtw = krw + (long)Bb * Ll * Hh * DHd;

  hipLaunchKernelGGL(rope_table_k, dim3((Ll * 64) / 256), dim3(256), 0, stream, table);
  hipLaunchKernelGGL(pre_k, dim3(Bb * NCc * Hh * 16), dim3(256), 0, stream,
                     (const float4*)q, (const float4*)k, (const float4*)v,
                     (const float4*)table, (ushort4*)qrw, (ushort4*)krw, vtw);
  hipLaunchKernelGGL(attn_k, dim3(Bb * NCc * Hh * 16), dim3(256), 0, stream,
                     qrw, krw, vtw, out);
}